// Round 2
// baseline (37242.731 us; speedup 1.0000x reference)
//
#include <hip/hip_runtime.h>
#include <hip/hip_bf16.h>
#include <math.h>

#define NLAYERS 6
#define NHEADS  8
#define HDIM    64
#define DMODEL  512
#define FDIM    2048
#define BSZ     8
#define LSRC    512
#define LTGT    256
#define VOCAB   32000

// ---------- embedding + (buggy) positional encoding ----------
// pe[b, 2i] = sin(b * 10000^(-2i/D)), pe[b, 2i+1] = cos(same) — depends on the
// batch index only (faithful to the reference's pe[:x.size(0)] slice bug).
__global__ __launch_bounds__(256) void embed_pe_kernel(
    const int* __restrict__ tok, const float* __restrict__ emb,
    float* __restrict__ out, int S)
{
    int i = blockIdx.x * 256 + threadIdx.x;   // over B*S*512
    int d  = i & 511;
    int bs = i >> 9;
    int b  = bs / S;
    int t  = tok[bs];
    float e   = emb[(size_t)t * DMODEL + d];
    float dv  = expf(-(float)(d & ~1) * 0.017988946039016f);  // ln(10000)/512
    float ang = (float)b * dv;
    float pe  = (d & 1) ? cosf(ang) : sinf(ang);
    out[i] = e + pe;
}

// ---------- layernorm (row = 512) ----------
__global__ __launch_bounds__(256) void layernorm_kernel(
    const float* __restrict__ x, const float* __restrict__ g,
    const float* __restrict__ b, float* __restrict__ out)
{
    int row = blockIdx.x;
    int tid = threadIdx.x;
    const float* xr = x + (size_t)row * DMODEL;
    float v0 = xr[tid], v1 = xr[tid + 256];
    __shared__ float red[256];
    red[tid] = v0 + v1;
    __syncthreads();
    for (int s = 128; s; s >>= 1) { if (tid < s) red[tid] += red[tid + s]; __syncthreads(); }
    float mean = red[0] * (1.0f / 512.0f);
    __syncthreads();
    float d0 = v0 - mean, d1 = v1 - mean;
    red[tid] = d0 * d0 + d1 * d1;
    __syncthreads();
    for (int s = 128; s; s >>= 1) { if (tid < s) red[tid] += red[tid + s]; __syncthreads(); }
    float rstd = rsqrtf(red[0] * (1.0f / 512.0f) + 1e-6f);
    float* orow = out + (size_t)row * DMODEL;
    orow[tid]       = d0 * rstd * g[tid]       + b[tid];
    orow[tid + 256] = d1 * rstd * g[tid + 256] + b[tid + 256];
}

// ---------- fp32 tiled GEMM: C[M,N] = A[M,K] @ B[K,N] + bias
//            (+ residual) (ReLU optional). M%64==0, N%64==0, K%16==0.
__global__ __launch_bounds__(256) void gemm_kernel(
    const float* __restrict__ A, const float* __restrict__ B,
    const float* __restrict__ bias, const float* __restrict__ residual,
    float* __restrict__ C, int M, int N, int K, int relu)
{
    __shared__ float As[16][65];   // [k][row]
    __shared__ float Bs[16][65];   // [k][col]
    int tid = threadIdx.x;
    int tx = tid & 15;             // 4 output cols each
    int ty = tid >> 4;             // 4 output rows each
    int brow = blockIdx.y * 64;
    int bcol = blockIdx.x * 64;
    float acc[4][4] = {};
    for (int k0 = 0; k0 < K; k0 += 16) {
        #pragma unroll
        for (int i = 0; i < 4; i++) {
            int idx = tid + i * 256;     // 0..1023
            int r = idx >> 4, c = idx & 15;
            As[c][r] = A[(size_t)(brow + r) * K + k0 + c];
        }
        #pragma unroll
        for (int i = 0; i < 4; i++) {
            int idx = tid + i * 256;
            int r = idx >> 6, c = idx & 63;
            Bs[r][c] = B[(size_t)(k0 + r) * N + bcol + c];
        }
        __syncthreads();
        #pragma unroll
        for (int kk = 0; kk < 16; kk++) {
            float a[4], b[4];
            #pragma unroll
            for (int i = 0; i < 4; i++) a[i] = As[kk][ty * 4 + i];
            #pragma unroll
            for (int j = 0; j < 4; j++) b[j] = Bs[kk][tx * 4 + j];
            #pragma unroll
            for (int i = 0; i < 4; i++)
                #pragma unroll
                for (int j = 0; j < 4; j++) acc[i][j] += a[i] * b[j];
        }
        __syncthreads();
    }
    #pragma unroll
    for (int i = 0; i < 4; i++) {
        int row = brow + ty * 4 + i;
        #pragma unroll
        for (int j = 0; j < 4; j++) {
            int col = bcol + tx * 4 + j;
            float v = acc[i][j] + bias[col];
            if (residual) v += residual[(size_t)row * N + col];
            if (relu) v = fmaxf(v, 0.0f);
            C[(size_t)row * N + col] = v;
        }
    }
}

// ---------- attention: one block per (b, h, q) ----------
// Q:[B,SQ,512] K,V:[B,SK,512] row-major; head h occupies cols [h*64, h*64+64).
// mask_mode 0: mask[B*SK] (broadcast over q); 1: mask[B*SQ*SK]
__global__ __launch_bounds__(256) void attn_kernel(
    const float* __restrict__ Q, const float* __restrict__ K,
    const float* __restrict__ V, const int* __restrict__ mask,
    int mask_mode, float* __restrict__ out, int SQ, int SK)
{
    int q = blockIdx.x, h = blockIdx.y, b = blockIdx.z;
    int tid = threadIdx.x;
    const int HD = NHEADS * HDIM;   // 512
    __shared__ float sc[512];
    __shared__ float qv[64];
    __shared__ float red[256];
    __shared__ float part[4][64];

    const float* qp = Q + ((size_t)b * SQ + q) * HD + h * HDIM;
    if (tid < 64) qv[tid] = qp[tid];
    __syncthreads();

    // scores
    for (int k = tid; k < SK; k += 256) {
        const float* kp = K + ((size_t)b * SK + k) * HD + h * HDIM;
        float s = 0.0f;
        #pragma unroll
        for (int d = 0; d < HDIM; d++) s += qv[d] * kp[d];
        s *= 0.125f;   // 1/sqrt(64)
        int mv = mask_mode ? mask[((size_t)b * SQ + q) * SK + k]
                           : mask[(size_t)b * SK + k];
        if (mv == 0) s = -1e9f;
        sc[k] = s;
    }
    __syncthreads();

    // max
    float m = -INFINITY;
    for (int k = tid; k < SK; k += 256) m = fmaxf(m, sc[k]);
    red[tid] = m; __syncthreads();
    for (int s = 128; s; s >>= 1) { if (tid < s) red[tid] = fmaxf(red[tid], red[tid + s]); __syncthreads(); }
    m = red[0]; __syncthreads();

    // exp + sum
    float ssum = 0.0f;
    for (int k = tid; k < SK; k += 256) { float e = expf(sc[k] - m); sc[k] = e; ssum += e; }
    red[tid] = ssum; __syncthreads();
    for (int s = 128; s; s >>= 1) { if (tid < s) red[tid] += red[tid + s]; __syncthreads(); }
    float denom = red[0]; __syncthreads();

    // weighted sum over V
    int d = tid & 63, g = tid >> 6;
    float o = 0.0f;
    for (int k = g; k < SK; k += 4)
        o += sc[k] * V[((size_t)b * SK + k) * HD + h * HDIM + d];
    part[g][d] = o;
    __syncthreads();
    if (tid < 64) {
        float r = (part[0][tid] + part[1][tid] + part[2][tid] + part[3][tid]) / denom;
        out[((size_t)b * SQ + q) * HD + h * HDIM + tid] = r;
    }
}

// ---------- in-place per-row log-softmax over fp32 logits ----------
__global__ __launch_bounds__(256) void logsoftmax_kernel(float* __restrict__ p, int N)
{
    int row = blockIdx.x, tid = threadIdx.x;
    float* r = p + (size_t)row * N;
    __shared__ float red[256];
    float m = -INFINITY;
    for (int i = tid; i < N; i += 256) m = fmaxf(m, r[i]);
    red[tid] = m; __syncthreads();
    for (int s = 128; s; s >>= 1) { if (tid < s) red[tid] = fmaxf(red[tid], red[tid + s]); __syncthreads(); }
    m = red[0]; __syncthreads();
    float ssum = 0.0f;
    for (int i = tid; i < N; i += 256) ssum += expf(r[i] - m);
    red[tid] = ssum; __syncthreads();
    for (int s = 128; s; s >>= 1) { if (tid < s) red[tid] += red[tid + s]; __syncthreads(); }
    float lse = m + logf(red[0]);
    __syncthreads();
    for (int i = tid; i < N; i += 256) r[i] = r[i] - lse;
}

// ---------- orchestration ----------
extern "C" void kernel_launch(void* const* d_in, const int* in_sizes, int n_in,
                              void* d_out, int out_size, void* d_ws, size_t ws_size,
                              hipStream_t stream)
{
    (void)in_sizes; (void)n_in; (void)out_size;
    const int* src     = (const int*)d_in[0];
    const int* tgt     = (const int*)d_in[1];
    const int* msk_src = (const int*)d_in[2];
    const int* msk_tgt = (const int*)d_in[3];
    const float* src_emb = (const float*)d_in[4];
    const float* tgt_emb = (const float*)d_in[5];
    const float* ew[16]; for (int i = 0; i < 16; i++) ew[i] = (const float*)d_in[6 + i];
    const float* dw[16]; for (int i = 0; i < 16; i++) dw[i] = (const float*)d_in[22 + i];
    const float* dln3_g = (const float*)d_in[38];
    const float* dln3_b = (const float*)d_in[39];
    const float* encn_g = (const float*)d_in[40];
    const float* encn_b = (const float*)d_in[41];
    const float* decn_g = (const float*)d_in[42];
    const float* decn_b = (const float*)d_in[43];
    const float* gen_w  = (const float*)d_in[44];
    const float* gen_b  = (const float*)d_in[45];

    const size_t SLOT = (size_t)4096 * 512;   // 2M floats = 8 MB
    float* ws = (float*)d_ws;
    // xn ALWAYS lives in d_ws (generator GEMM reads it while writing d_out).
    float* xn = ws;
    // The six big slots live in d_ws if it's large enough, else in the (dead
    // until generator) 262 MB d_out region. ws_size is constant across calls,
    // so the branch is graph-capture safe.
    bool ws_ok = ws_size >= 7 * SLOT * sizeof(float);
    float* big = ws_ok ? (ws + SLOT) : (float*)d_out;
    float* x   = big;                // activations (enc x, later dec y)
    float* z   = big + SLOT;         // encoder memory (persists)
    float* sq  = big + 2 * SLOT;     // Q
    float* skb = big + 3 * SLOT;     // K
    float* sv  = big + 4 * SLOT;     // V
    float* sa  = big + 5 * SLOT;     // attention output
    float* ff  = sq;                 // FF mid aliases q/k/v/attn (8M floats)

    auto gemm = [&](const float* A, const float* B, const float* bias,
                    const float* res, float* C, int M, int N, int K, int relu) {
        gemm_kernel<<<dim3(N / 64, M / 64), 256, 0, stream>>>(
            A, B, bias, res, C, M, N, K, relu);
    };

    const int Me = BSZ * LSRC;   // 4096
    const int Md = BSZ * LTGT;   // 2048
    const int WSQ = DMODEL * DMODEL;  // per-layer attn weight stride

    // ===== encoder =====
    embed_pe_kernel<<<(Me * DMODEL) / 256, 256, 0, stream>>>(src, src_emb, x, LSRC);
    for (int i = 0; i < NLAYERS; i++) {
        layernorm_kernel<<<Me, 256, 0, stream>>>(x, ew[12] + i * 512, ew[13] + i * 512, xn);
        gemm(xn, ew[0] + i * WSQ, ew[1] + i * 512, nullptr, sq,  Me, 512, 512, 0);
        gemm(xn, ew[2] + i * WSQ, ew[3] + i * 512, nullptr, skb, Me, 512, 512, 0);
        gemm(xn, ew[4] + i * WSQ, ew[5] + i * 512, nullptr, sv,  Me, 512, 512, 0);
        attn_kernel<<<dim3(LSRC, NHEADS, BSZ), 256, 0, stream>>>(
            sq, skb, sv, msk_src, 0, sa, LSRC, LSRC);
        gemm(sa, ew[6] + i * WSQ, ew[7] + i * 512, x, x, Me, 512, 512, 0);
        layernorm_kernel<<<Me, 256, 0, stream>>>(x, ew[14] + i * 512, ew[15] + i * 512, xn);
        gemm(xn, ew[8]  + i * (512 * 2048), ew[9]  + i * 2048, nullptr, ff, Me, 2048, 512, 1);
        gemm(ff, ew[10] + i * (2048 * 512), ew[11] + i * 512,  x,       x,  Me, 512, 2048, 0);
    }
    layernorm_kernel<<<Me, 256, 0, stream>>>(x, encn_g, encn_b, z);

    // ===== decoder =====
    embed_pe_kernel<<<(Md * DMODEL) / 256, 256, 0, stream>>>(tgt, tgt_emb, x, LTGT);
    for (int i = 0; i < NLAYERS; i++) {
        // self-attention (causal mask)
        layernorm_kernel<<<Md, 256, 0, stream>>>(x, dw[12] + i * 512, dw[13] + i * 512, xn);
        gemm(xn, dw[0] + i * WSQ, dw[1] + i * 512, nullptr, sq,  Md, 512, 512, 0);
        gemm(xn, dw[2] + i * WSQ, dw[3] + i * 512, nullptr, skb, Md, 512, 512, 0);
        gemm(xn, dw[4] + i * WSQ, dw[5] + i * 512, nullptr, sv,  Md, 512, 512, 0);
        attn_kernel<<<dim3(LTGT, NHEADS, BSZ), 256, 0, stream>>>(
            sq, skb, sv, msk_tgt, 1, sa, LTGT, LTGT);
        gemm(sa, dw[6] + i * WSQ, dw[7] + i * 512, x, x, Md, 512, 512, 0);
        // cross-attention (shares the same per-layer attention weights)
        layernorm_kernel<<<Md, 256, 0, stream>>>(x, dw[14] + i * 512, dw[15] + i * 512, xn);
        gemm(xn, dw[0] + i * WSQ, dw[1] + i * 512, nullptr, sq,  Md, 512, 512, 0);
        gemm(z,  dw[2] + i * WSQ, dw[3] + i * 512, nullptr, skb, Me, 512, 512, 0);
        gemm(z,  dw[4] + i * WSQ, dw[5] + i * 512, nullptr, sv,  Me, 512, 512, 0);
        attn_kernel<<<dim3(LTGT, NHEADS, BSZ), 256, 0, stream>>>(
            sq, skb, sv, msk_src, 0, sa, LTGT, LSRC);
        gemm(sa, dw[6] + i * WSQ, dw[7] + i * 512, x, x, Md, 512, 512, 0);
        // feed-forward
        layernorm_kernel<<<Md, 256, 0, stream>>>(x, dln3_g + i * 512, dln3_b + i * 512, xn);
        gemm(xn, dw[8]  + i * (512 * 2048), dw[9]  + i * 2048, nullptr, ff, Md, 2048, 512, 1);
        gemm(ff, dw[10] + i * (2048 * 512), dw[11] + i * 512,  x,       x,  Md, 512, 2048, 0);
    }
    layernorm_kernel<<<Md, 256, 0, stream>>>(x, decn_g, decn_b, xn);

    // ===== generator + log-softmax (fp32 logits in d_out, then in-place) =====
    gemm_kernel<<<dim3(VOCAB / 64, Md / 64), 256, 0, stream>>>(
        xn, gen_w, gen_b, nullptr, (float*)d_out, Md, VOCAB, 512, 0);
    logsoftmax_kernel<<<Md, 256, 0, stream>>>((float*)d_out, VOCAB);
}